// Round 3
// baseline (159.194 us; speedup 1.0000x reference)
//
#include <hip/hip_runtime.h>
#include <math.h>

#define NPTS 8192
#define NB 4
#define BLK 256
#define Q 8              // queries per thread (phase 1)
#define TILE 512         // ref points staged in LDS per tile (8 KB as float4)
#define NSEG 16          // ref-dim segments (blocks per bd per qchunk)
#define QCHUNKS (NPTS / (BLK * Q))     // 4
#define BLOCKS_PER_BD (NSEG * QCHUNKS) // 64
#define CTRL_FLOATS 64   // 256 B control region at start of ws

// Single fused kernel.
// Phase 1 (all 512 blocks): partial[bd][seg][q] = min over refs in segment of
//   (|r|^2 - 2 q.r)    (|q|^2 added in phase 2; min commutes with +|q|^2)
// Fan-in: last-arriving block per bd combines segments, sqrt, sums; last of
// the 8 bd-reducers writes the final mean to out.
__global__ __launch_bounds__(BLK) void chamfer_fused(
    const float* __restrict__ tmpl, const float* __restrict__ src,
    float* __restrict__ ws, float* __restrict__ out)
{
    int*   cnt     = (int*)ws;            // [8] per-bd arrival counters (memset 0)
    int*   cnt2    = (int*)ws + 8;        // final fan-in counter        (memset 0)
    float* acc     = ws + 9;              // global sum accumulator      (memset 0)
    float* partial = ws + CTRL_FLOATS;    // [8][NSEG][NPTS]

    __shared__ float4 lds[TILE];
    __shared__ float  wsum[BLK / 64];
    __shared__ int    ticket;

    const int bd  = blockIdx.z;           // 0..7 = b*2 + dir
    const int b   = bd >> 1;
    const int dir = bd & 1;
    const float* qp = (dir ? src : tmpl) + (size_t)b * NPTS * 3;
    const float* rp = (dir ? tmpl : src) + (size_t)b * NPTS * 3;
    const int tid   = threadIdx.x;
    const int qbase = blockIdx.x * (BLK * Q);

    // ---------------- phase 1 ----------------
    float qx[Q], qy[Q], qz[Q], mn[Q];
#pragma unroll
    for (int k = 0; k < Q; k++) {
        const int qi = qbase + k * BLK + tid;
        qx[k] = qp[3 * qi + 0];
        qy[k] = qp[3 * qi + 1];
        qz[k] = qp[3 * qi + 2];
        mn[k] = 3.4e38f;
    }

    const int seg_len   = NPTS / NSEG;    // 512
    const int seg_start = blockIdx.y * seg_len;
    for (int ts = 0; ts < seg_len; ts += TILE) {
        __syncthreads();
        for (int i = tid; i < TILE; i += BLK) {
            const int ri = seg_start + ts + i;
            const float rx = rp[3 * ri + 0];
            const float ry = rp[3 * ri + 1];
            const float rz = rp[3 * ri + 2];
            lds[i] = make_float4(-2.f * rx, -2.f * ry, -2.f * rz,
                                 rx * rx + ry * ry + rz * rz);
        }
        __syncthreads();
#pragma unroll 4
        for (int j = 0; j < TILE; j++) {
            const float4 r = lds[j];
#pragma unroll
            for (int k = 0; k < Q; k++) {
                float t = fmaf(qx[k], r.x, r.w);
                t = fmaf(qy[k], r.y, t);
                t = fmaf(qz[k], r.z, t);
                mn[k] = fminf(mn[k], t);
            }
        }
    }

    const size_t pbase = ((size_t)bd * NSEG + blockIdx.y) * NPTS;
#pragma unroll
    for (int k = 0; k < Q; k++)
        partial[pbase + qbase + k * BLK + tid] = mn[k];

    // ---------------- fan-in ticket ----------------
    __threadfence();                 // release: my partials visible device-wide
    __syncthreads();                 // all threads' stores+fences done
    if (tid == 0) ticket = atomicAdd(&cnt[bd], 1);
    __syncthreads();
    if (ticket != BLOCKS_PER_BD - 1) return;   // not last arrival for this bd
    __threadfence();                 // acquire: see all blocks' partials

    // ---------------- phase 2: reduce this bd ----------------
    float sum = 0.f;
    const size_t bdbase = (size_t)bd * NSEG * NPTS;
#pragma unroll 2
    for (int qb = 0; qb < NPTS / BLK; qb++) {    // 32 iters
        const int qi = qb * BLK + tid;
        float m = partial[bdbase + qi];
#pragma unroll
        for (int s = 1; s < NSEG; s++)
            m = fminf(m, partial[bdbase + (size_t)s * NPTS + qi]);
        const float x = qp[3 * qi + 0];
        const float y = qp[3 * qi + 1];
        const float z = qp[3 * qi + 2];
        sum += sqrtf(fmaxf(x * x + y * y + z * z + m, 0.f));
    }

    // wave + block reduction of sum
#pragma unroll
    for (int off = 32; off > 0; off >>= 1)
        sum += __shfl_down(sum, off, 64);
    const int lane = tid & 63, wid = tid >> 6;
    if (lane == 0) wsum[wid] = sum;
    __syncthreads();
    if (tid == 0) {
        float s = 0.f;
#pragma unroll
        for (int w = 0; w < BLK / 64; w++) s += wsum[w];
        atomicAdd(acc, s);           // device-scope
        __threadfence();
        const int o2 = atomicAdd(cnt2, 1);
        if (o2 == 2 * NB - 1) {      // last of the 8 bd-reducers
            __threadfence();
            const float tot = atomicAdd(acc, 0.0f);  // RMW: returns full sum
            // mean over NPTS * avg 2 dirs * mean NB batches = /65536
            *out = tot * (1.0f / 65536.0f);
        }
    }
}

extern "C" void kernel_launch(void* const* d_in, const int* in_sizes, int n_in,
                              void* d_out, int out_size, void* d_ws, size_t ws_size,
                              hipStream_t stream) {
    const float* tmpl = (const float*)d_in[0];
    const float* src  = (const float*)d_in[1];
    float* out = (float*)d_out;
    float* ws  = (float*)d_ws;

    // zero the 64-byte control region (counters + accumulator)
    hipMemsetAsync(d_ws, 0, 64, stream);

    dim3 grid(QCHUNKS, NSEG, 2 * NB);   // 4 x 16 x 8 = 512 blocks
    chamfer_fused<<<grid, BLK, 0, stream>>>(tmpl, src, ws, out);
}

// Round 4
// 105.735 us; speedup vs baseline: 1.5056x; 1.5056x over previous
//
#include <hip/hip_runtime.h>
#include <math.h>

#define NPTS 8192
#define NB 4
#define BLK 256
#define Q 16             // queries per thread, as explicit named scalars
#define TILE 256         // ref points staged in LDS per tile (== BLK)
#define QCHUNKS (NPTS / (BLK * Q))   // 2

#define REPEAT16(M) M(0) M(1) M(2) M(3) M(4) M(5) M(6) M(7) \
                    M(8) M(9) M(10) M(11) M(12) M(13) M(14) M(15)

// Kernel 1: partial[bd][seg][q] = min over refs in segment of (|r|^2 - 2 q.r)
// (|q|^2 added in kernel 2; min commutes with +|q|^2 and the clamp.)
// Q=16 explicit scalars: 64 fma/min per ds_read_b128 -> LDS pipe ~35%,
// and forces the compiler to keep query state in VGPRs (round-1/2 builds
// reported VGPR_Count=36, impossible for register-resident Q=8 state).
template <int NSEG>
__global__ __launch_bounds__(BLK) void chamfer_partial(
    const float* __restrict__ tmpl, const float* __restrict__ src,
    float* __restrict__ partial)
{
    __shared__ float4 lds[TILE];
    const int bd  = blockIdx.z;          // 0..7 = b*2 + dir
    const int b   = bd >> 1;
    const int dir = bd & 1;
    const float* qp = (dir ? src : tmpl) + (size_t)b * NPTS * 3;
    const float* rp = (dir ? tmpl : src) + (size_t)b * NPTS * 3;
    const int tid   = threadIdx.x;
    const int qbase = blockIdx.x * (BLK * Q);

#define DECL(i) float qx##i, qy##i, qz##i, mn##i = 3.4e38f;
    REPEAT16(DECL)
#undef DECL
#define LOADQ(i) { const int qi = qbase + (i) * BLK + tid;              \
                   qx##i = qp[3 * qi + 0];                              \
                   qy##i = qp[3 * qi + 1];                              \
                   qz##i = qp[3 * qi + 2]; }
    REPEAT16(LOADQ)
#undef LOADQ

    const int seg_len   = NPTS / NSEG;   // compile-time
    const int seg_start = blockIdx.y * seg_len;
    for (int ts = 0; ts < seg_len; ts += TILE) {
        __syncthreads();
        {
            const int ri = seg_start + ts + tid;   // TILE == BLK: 1 pt/thread
            const float rx = rp[3 * ri + 0];
            const float ry = rp[3 * ri + 1];
            const float rz = rp[3 * ri + 2];
            lds[tid] = make_float4(-2.f * rx, -2.f * ry, -2.f * rz,
                                   rx * rx + ry * ry + rz * rz);
        }
        __syncthreads();
#pragma unroll 2
        for (int j = 0; j < TILE; j++) {
            const float4 r = lds[j];
            float t;
#define STEP(i) t = fmaf(qx##i, r.x, r.w);   \
                t = fmaf(qy##i, r.y, t);     \
                t = fmaf(qz##i, r.z, t);     \
                mn##i = fminf(mn##i, t);
            REPEAT16(STEP)
#undef STEP
        }
    }

    const size_t base = ((size_t)bd * NSEG + blockIdx.y) * NPTS + qbase + tid;
#define STORE(i) partial[base + (size_t)(i) * BLK] = mn##i;
    REPEAT16(STORE)
#undef STORE
}

// Kernel 2: combine segment partials, add |q|^2, clamp, sqrt, global mean.
template <int NSEG>
__global__ __launch_bounds__(BLK) void chamfer_reduce(
    const float* __restrict__ tmpl, const float* __restrict__ src,
    const float* __restrict__ partial, float* __restrict__ out)
{
    const int t  = blockIdx.x * BLK + threadIdx.x;  // 0 .. 8*NPTS-1
    const int bd = t >> 13;                         // / NPTS
    const int qi = t & (NPTS - 1);
    const int b  = bd >> 1;
    const int dir = bd & 1;
    const float* qp = (dir ? src : tmpl) + (size_t)b * NPTS * 3;

    float v[NSEG];
#pragma unroll
    for (int s = 0; s < NSEG; s++)
        v[s] = partial[((size_t)bd * NSEG + s) * NPTS + qi];
#pragma unroll
    for (int w = NSEG; w > 1; w >>= 1)
#pragma unroll
        for (int s = 0; s < w / 2; s++)
            v[s] = fminf(v[s], v[s + w / 2]);

    const float qx = qp[3 * qi + 0];
    const float qy = qp[3 * qi + 1];
    const float qz = qp[3 * qi + 2];
    const float sq = qx * qx + qy * qy + qz * qz;

    float val = sqrtf(fmaxf(sq + v[0], 0.f));

    // wave reduction (64 lanes)
#pragma unroll
    for (int off = 32; off > 0; off >>= 1)
        val += __shfl_down(val, off, 64);

    __shared__ float wsum[BLK / 64];
    const int lane = threadIdx.x & 63;
    const int wid  = threadIdx.x >> 6;
    if (lane == 0) wsum[wid] = val;
    __syncthreads();
    if (threadIdx.x == 0) {
        float s = 0.f;
#pragma unroll
        for (int w = 0; w < BLK / 64; w++) s += wsum[w];
        // mean over N (8192) * avg 2 dirs * mean 4 batches = /65536
        atomicAdd(out, s * (1.0f / 65536.0f));
    }
}

extern "C" void kernel_launch(void* const* d_in, const int* in_sizes, int n_in,
                              void* d_out, int out_size, void* d_ws, size_t ws_size,
                              hipStream_t stream) {
    const float* tmpl = (const float*)d_in[0];
    const float* src  = (const float*)d_in[1];
    float* out     = (float*)d_out;
    float* partial = (float*)d_ws;

    // choose nseg (power of 2, <=32) to fit workspace: 8*nseg*NPTS*4 bytes
    int nseg = 32;
    while (nseg > 1 && (size_t)8 * nseg * NPTS * sizeof(float) > ws_size)
        nseg >>= 1;

    hipMemsetAsync(d_out, 0, sizeof(float), stream);

    const int g2 = (2 * NB * NPTS) / BLK;
    switch (nseg) {
    case 32: {
        dim3 g1(QCHUNKS, 32, 2 * NB);
        chamfer_partial<32><<<g1, BLK, 0, stream>>>(tmpl, src, partial);
        chamfer_reduce<32><<<g2, BLK, 0, stream>>>(tmpl, src, partial, out);
        break;
    }
    case 16: {
        dim3 g1(QCHUNKS, 16, 2 * NB);
        chamfer_partial<16><<<g1, BLK, 0, stream>>>(tmpl, src, partial);
        chamfer_reduce<16><<<g2, BLK, 0, stream>>>(tmpl, src, partial, out);
        break;
    }
    case 8: {
        dim3 g1(QCHUNKS, 8, 2 * NB);
        chamfer_partial<8><<<g1, BLK, 0, stream>>>(tmpl, src, partial);
        chamfer_reduce<8><<<g2, BLK, 0, stream>>>(tmpl, src, partial, out);
        break;
    }
    case 4: {
        dim3 g1(QCHUNKS, 4, 2 * NB);
        chamfer_partial<4><<<g1, BLK, 0, stream>>>(tmpl, src, partial);
        chamfer_reduce<4><<<g2, BLK, 0, stream>>>(tmpl, src, partial, out);
        break;
    }
    case 2: {
        dim3 g1(QCHUNKS, 2, 2 * NB);
        chamfer_partial<2><<<g1, BLK, 0, stream>>>(tmpl, src, partial);
        chamfer_reduce<2><<<g2, BLK, 0, stream>>>(tmpl, src, partial, out);
        break;
    }
    default: {
        dim3 g1(QCHUNKS, 1, 2 * NB);
        chamfer_partial<1><<<g1, BLK, 0, stream>>>(tmpl, src, partial);
        chamfer_reduce<1><<<g2, BLK, 0, stream>>>(tmpl, src, partial, out);
        break;
    }
    }
}